// Round 2
// baseline (343.926 us; speedup 1.0000x reference)
//
#include <hip/hip_runtime.h>
#include <cstdint>
#include <cstddef>

#define DD 512
#define TT 16384
#define CC 8192
#define SPLITC 32
#define EPS_DIV 1e-6f
#define EPS_NORM 1e-12f
#define EPS_PD 1e-6f

typedef _Float16 half8 __attribute__((ext_vector_type(8)));
typedef _Float16 half4 __attribute__((ext_vector_type(4)));
typedef float floatx4 __attribute__((ext_vector_type(4)));

// async global->LDS, 16B per lane; lds base must be wave-uniform
#define GLDS16(g, l) __builtin_amdgcn_global_load_lds( \
    (const __attribute__((address_space(1))) void*)(g), \
    (__attribute__((address_space(3))) void*)(l), 16, 0, 0)

// ---------------- split fp32 -> (hi, lo) fp16, [row][0:512]=hi [512:1024]=lo ----------------
__global__ __launch_bounds__(128) void k_split(const float* __restrict__ src,
                                               _Float16* __restrict__ dst) {
  const int row = blockIdx.x;
  const int col = threadIdx.x * 4;
  float4 v = *(const float4*)(src + (size_t)row * DD + col);
  half4 h, l;
  h.x = (_Float16)v.x; l.x = (_Float16)(v.x - (float)h.x);
  h.y = (_Float16)v.y; l.y = (_Float16)(v.y - (float)h.y);
  h.z = (_Float16)v.z; l.z = (_Float16)(v.z - (float)h.z);
  h.w = (_Float16)v.w; l.w = (_Float16)(v.w - (float)h.w);
  *(half4*)(dst + (size_t)row * 1024 + col) = h;
  *(half4*)(dst + (size_t)row * 1024 + 512 + col) = l;
}

// ---------------- cast fp32 -> fp16 (hi only), [row][512] ----------------
__global__ __launch_bounds__(128) void k_cast16(const float* __restrict__ src,
                                                _Float16* __restrict__ dst) {
  const int row = blockIdx.x;
  const int col = threadIdx.x * 4;
  float4 v = *(const float4*)(src + (size_t)row * DD + col);
  half4 h;
  h.x = (_Float16)v.x; h.y = (_Float16)v.y;
  h.z = (_Float16)v.z; h.w = (_Float16)v.w;
  *(half4*)(dst + (size_t)row * DD + col) = h;
}

// ---------------- imp = cb @ W^T via split-fp16 3-pass MFMA ----------------
// A=cbs [CC][1024] (hi|lo), B=Ws [DD][1024]. imp = ch.wh + ch.wl + cl.wh.
// 128x128 tile, 4 waves 2x2, BK=64, double-buffered LDS, writes imp fp32 + ih fp16.
__global__ __launch_bounds__(256) void k_gemm_mfma(
    const _Float16* __restrict__ cbs, const _Float16* __restrict__ Ws,
    float* __restrict__ imp, _Float16* __restrict__ ih) {
  __shared__ __align__(16) char smem[65536];  // A0,B0,A1,B1 @ 16KB each
  const int tid = threadIdx.x;
  const int w = tid >> 6, lane = tid & 63;
  const int quad = lane >> 4, l15 = lane & 15;
  const int wm = (w & 1) * 64, wn = (w >> 1) * 64;
  const int c0 = blockIdx.x * 128;
  const int n0 = blockIdx.y * 128;

  const int srow8 = lane >> 3;
  const int scol = ((lane & 7) ^ srow8) << 3;  // halfs, XOR-swizzled col block
  size_t arow[4], brow[4];
#pragma unroll
  for (int j = 0; j < 4; ++j) {
    arow[j] = (size_t)(c0 + j * 32 + w * 8 + srow8) * 1024 + scol;
    brow[j] = (size_t)(n0 + j * 32 + w * 8 + srow8) * 1024 + scol;
  }
  int aoff[4], boff[4];
#pragma unroll
  for (int i = 0; i < 4; ++i) {
    aoff[i] = ((wm + i * 16 + l15) * 64 + ((quad ^ (l15 & 7)) << 3)) * 2;
    boff[i] = ((wn + i * 16 + l15) * 64 + ((quad ^ (l15 & 7)) << 3)) * 2;
  }

  auto stage = [&](int buf, int ak, int bk) {
    char* ab = smem + buf * 32768;
    char* bb = ab + 16384;
#pragma unroll
    for (int j = 0; j < 4; ++j) {
      GLDS16(cbs + arow[j] + ak, (_Float16*)ab + (j * 32 + w * 8) * 64);
      GLDS16(Ws  + brow[j] + bk, (_Float16*)bb + (j * 32 + w * 8) * 64);
    }
  };

  floatx4 acc[4][4] = {};
  stage(0, 0, 0);
#pragma unroll 2
  for (int it = 0; it < 24; ++it) {   // 3 passes x 8 k-steps
    __syncthreads();
    if (it < 23) {
      const int n = it + 1;
      const int p = n >> 3, kk = n & 7;
      const int ak = ((p == 2) ? 512 : 0) + kk * 64;
      const int bk = ((p == 1) ? 512 : 0) + kk * 64;
      stage(n & 1, ak, bk);
    }
    const char* ab = smem + (it & 1) * 32768;
    const char* bb = ab + 16384;
#pragma unroll
    for (int ks = 0; ks < 2; ++ks) {
      const int kx = ks * 64;  // byte XOR for col-block +4 (rows are 128B here)
      half8 a[4], b[4];
#pragma unroll
      for (int mi = 0; mi < 4; ++mi)
        a[mi] = *(const half8*)(ab + (aoff[mi] ^ kx));
#pragma unroll
      for (int ni = 0; ni < 4; ++ni)
        b[ni] = *(const half8*)(bb + (boff[ni] ^ kx));
#pragma unroll
      for (int mi = 0; mi < 4; ++mi)
#pragma unroll
        for (int ni = 0; ni < 4; ++ni)
          acc[mi][ni] = __builtin_amdgcn_mfma_f32_16x16x32_f16(
              a[mi], b[ni], acc[mi][ni], 0, 0, 0);
    }
  }
  // C/D layout: col=lane&15, row=quad*4+reg
#pragma unroll
  for (int mi = 0; mi < 4; ++mi)
#pragma unroll
    for (int r = 0; r < 4; ++r) {
      const int c = c0 + wm + mi * 16 + quad * 4 + r;
#pragma unroll
      for (int ni = 0; ni < 4; ++ni) {
        const int d = n0 + wn + ni * 16 + l15;
        const float v = acc[mi][ni][r];
        imp[(size_t)c * DD + d] = v;
        ih[(size_t)c * DD + d] = (_Float16)v;
      }
    }
}

// ---------------- per-code squared norms (fp32) ----------------
__global__ __launch_bounds__(256) void k_row_norm2(
    const float* __restrict__ imp, float* __restrict__ cnorm) {
  const int lane = threadIdx.x & 63;
  const int row = blockIdx.x * 4 + (threadIdx.x >> 6);
  const float* p = imp + (size_t)row * DD + lane * 8;
  float4 a = *(const float4*)p;
  float4 b = *(const float4*)(p + 4);
  float s = a.x * a.x + a.y * a.y + a.z * a.z + a.w * a.w +
            b.x * b.x + b.y * b.y + b.z * b.z + b.w * b.w;
#pragma unroll
  for (int m = 1; m < 64; m <<= 1) s += __shfl_xor(s, m);
  if (lane == 0) cnorm[row] = s;
}

// ---------------- phase 1: fp16 hi.hi MFMA scores + per-row TOP-2 ----------------
// 256x256 tile, 8 waves (2Mx4N), BK=32, 4-buffer LDS ring, depth-3 prefetch with
// counted vmcnt (never 0 in main loop), raw s_barrier, register-pipelined frags:
// MFMA(t) interleaved with ds_read of tile t+1 (a-frags rotate, b double-buffered).
__global__ __launch_bounds__(512, 2) void k_dist_top2(
    const _Float16* __restrict__ xh, const _Float16* __restrict__ ih,
    const float* __restrict__ cnorm,
    float* __restrict__ bval, int* __restrict__ bidx) {
  __shared__ __align__(16) char smem[131072];  // ring: 4 x (A 16KB | B 16KB)
  const int tid = threadIdx.x;
  const int w = tid >> 6, lane = tid & 63;
  const int quad = lane >> 4, l15 = lane & 15;
  const int wr = w >> 2, wc = w & 3;  // 2 (M) x 4 (N) waves, 128x64 per wave
  const int r0 = blockIdx.x * 256;
  const int c0 = blockIdx.y * 256;

  // staging: per wave 32 rows of A and B per tile (2 GLDS16 each).
  // LDS dest is linear (base + lane*16); global source pre-swizzled:
  // chunk = slot ^ (row&3) ^ ((row>>2)&3)  (4 chunks of 8 halfs per 32-half row)
  const int rloc = lane >> 2;                                   // 0..15
  const int chunk = (lane & 3) ^ (rloc & 3) ^ ((rloc >> 2) & 3);
  const _Float16* pA0 = xh + (size_t)(r0 + w * 32 + rloc) * DD + chunk * 8;
  const _Float16* pA1 = pA0 + (size_t)16 * DD;
  const _Float16* pB0 = ih + (size_t)(c0 + w * 32 + rloc) * DD + chunk * 8;
  const _Float16* pB1 = pB0 + (size_t)16 * DD;
  const int ldsA0 = (w * 32) * 64;        // bytes within A region (row=64B)
  const int ldsA1 = ldsA0 + 16 * 64;
  const int ldsB0 = 16384 + ldsA0;
  const int ldsB1 = 16384 + ldsA1;

  // frag read offsets (inverse swizzle): slot = quad ^ (l15&3) ^ ((l15>>2)&3)
  const int slot = (quad ^ (l15 & 3) ^ ((l15 >> 2) & 3)) << 4;  // bytes
  int aoff[8], boff[4];
#pragma unroll
  for (int mi = 0; mi < 8; ++mi)
    aoff[mi] = (wr * 128 + mi * 16 + l15) * 64 + slot;
#pragma unroll
  for (int ni = 0; ni < 4; ++ni)
    boff[ni] = 16384 + (wc * 64 + ni * 16 + l15) * 64 + slot;

  float cn[4];
#pragma unroll
  for (int ni = 0; ni < 4; ++ni)
    cn[ni] = cnorm[c0 + wc * 64 + ni * 16 + l15];

  floatx4 acc[8][4] = {};
  half8 a[8], bX[4], bY[4];

  auto STAGE = [&](int t) {
    char* base = smem + (t & 3) * 32768;
    const size_t ko = (size_t)(t * 32);
    GLDS16(pA0 + ko, base + ldsA0);
    GLDS16(pA1 + ko, base + ldsA1);
    GLDS16(pB0 + ko, base + ldsB0);
    GLDS16(pB1 + ko, base + ldsB1);
  };

  // prologue: stage 3 tiles, wait tile 0, preload its fragments
  STAGE(0); STAGE(1); STAGE(2);
  asm volatile("s_waitcnt vmcnt(8)" ::: "memory");
  __builtin_amdgcn_s_barrier();
  __builtin_amdgcn_sched_barrier(0);
  {
    const char* ab = smem;  // buf 0
#pragma unroll
    for (int mi = 0; mi < 8; ++mi) a[mi] = *(const half8*)(ab + aoff[mi]);
#pragma unroll
    for (int ni = 0; ni < 4; ++ni) bX[ni] = *(const half8*)(ab + boff[ni]);
  }

// one K-tile iteration: stage t+3, confirm t+1 resident (counted vmcnt + barrier),
// then MFMA(t) interleaved with ds_read of tile t+1's fragments.
#define K_ITER(T, BCUR, BNXT, DO_STAGE, VMC, DO_READ)                          \
  {                                                                            \
    if (DO_STAGE) STAGE((T) + 3);                                              \
    asm volatile("s_waitcnt vmcnt(" #VMC ")" ::: "memory");                    \
    __builtin_amdgcn_s_barrier();                                              \
    __builtin_amdgcn_sched_barrier(0);                                         \
    asm volatile("s_waitcnt lgkmcnt(0)" ::: "memory");                         \
    __builtin_amdgcn_sched_barrier(0);                                         \
    const char* nb = smem + (((T) + 1) & 3) * 32768;                           \
    __builtin_amdgcn_s_setprio(1);                                             \
    _Pragma("unroll")                                                          \
    for (int mi = 0; mi < 8; ++mi) {                                           \
      _Pragma("unroll")                                                        \
      for (int ni = 0; ni < 4; ++ni)                                           \
        acc[mi][ni] = __builtin_amdgcn_mfma_f32_16x16x32_f16(                  \
            a[mi], BCUR[ni], acc[mi][ni], 0, 0, 0);                            \
      if (DO_READ) a[mi] = *(const half8*)(nb + aoff[mi]);                     \
    }                                                                          \
    if (DO_READ) {                                                             \
      _Pragma("unroll")                                                        \
      for (int ni = 0; ni < 4; ++ni)                                           \
        BNXT[ni] = *(const half8*)(nb + boff[ni]);                             \
    }                                                                          \
    __builtin_amdgcn_s_setprio(0);                                             \
  }

  K_ITER(0,  bX, bY, true,  8, true)
  K_ITER(1,  bY, bX, true,  8, true)
  K_ITER(2,  bX, bY, true,  8, true)
  K_ITER(3,  bY, bX, true,  8, true)
  K_ITER(4,  bX, bY, true,  8, true)
  K_ITER(5,  bY, bX, true,  8, true)
  K_ITER(6,  bX, bY, true,  8, true)
  K_ITER(7,  bY, bX, true,  8, true)
  K_ITER(8,  bX, bY, true,  8, true)
  K_ITER(9,  bY, bX, true,  8, true)
  K_ITER(10, bX, bY, true,  8, true)
  K_ITER(11, bY, bX, true,  8, true)
  K_ITER(12, bX, bY, true,  8, true)
  K_ITER(13, bY, bX, false, 4, true)
  K_ITER(14, bX, bY, false, 0, true)
  K_ITER(15, bY, bX, false, 0, false)
#undef K_ITER

  // ---- per-row top-2 over the block's 256 codes ----
  __syncthreads();
  float* rv = (float*)smem;            // [256][64] values (64KB), bank-swizzled
  int* ri = (int*)(smem + 65536);      // [256][64] indices (64KB)
#pragma unroll
  for (int mi = 0; mi < 8; ++mi)
#pragma unroll
    for (int r = 0; r < 4; ++r) {
      const int row = wr * 128 + mi * 16 + quad * 4 + r;
      float bv = 3.4e38f; int bi = 0x7fffffff;
#pragma unroll
      for (int ni = 0; ni < 4; ++ni) {
        const float v = fmaf(-2.0f, acc[mi][ni][r], cn[ni]);
        const int c = c0 + wc * 64 + ni * 16 + l15;  // ascends with ni
        if (v < bv) { bv = v; bi = c; }
      }
      const int e = wc * 16 + l15;                   // 0..63
      const int g = (row & 31) ^ ((row & 4) << 2);   // mixes quad bit into bank bit4
      const int col = e ^ g;
      rv[row * 64 + col] = bv;
      ri[row * 64 + col] = bi;
    }
  __syncthreads();
  {
    const int row = tid >> 1, h = tid & 1;           // 2 threads per row
    const int g = (row & 31) ^ ((row & 4) << 2);
    float v1 = 3.4e38f, v2 = 3.4e38f;
    int i1 = 0x7fffffff, i2 = 0x7fffffff;
#pragma unroll
    for (int j = 0; j < 32; ++j) {
      const int e = h * 32 + j;
      const int col = e ^ g;
      const float v = rv[row * 64 + col];
      const int i = ri[row * 64 + col];
      if (v < v1 || (v == v1 && i < i1)) { v2 = v1; i2 = i1; v1 = v; i1 = i; }
      else if (v < v2 || (v == v2 && i < i2)) { v2 = v; i2 = i; }
    }
    const float w1 = __shfl_xor(v1, 1), w2 = __shfl_xor(v2, 1);
    const int j1 = __shfl_xor(i1, 1), j2 = __shfl_xor(i2, 1);
    if (w1 < v1 || (w1 == v1 && j1 < i1)) {
      if (v1 < w2 || (v1 == w2 && i1 < j2)) { v2 = v1; i2 = i1; }
      else { v2 = w2; i2 = j2; }
      v1 = w1; i1 = j1;
    } else if (w1 < v2 || (w1 == v2 && j1 < i2)) { v2 = w1; i2 = j1; }
    if (h == 0) {
      const size_t o = ((size_t)blockIdx.y * TT + r0 + row) * 2;
      bval[o] = v1; bval[o + 1] = v2;
      bidx[o] = i1; bidx[o + 1] = i2;
    }
  }
}

// ---------------- epilogue: butterfly top-2 merge, exact rescore, rotation ----------------
__global__ __launch_bounds__(256) void k_epilogue(
    const float* __restrict__ x, const float* __restrict__ imp,
    const float* __restrict__ cnorm,
    const float* __restrict__ bval, const int* __restrict__ bidx,
    float* __restrict__ outq, float* __restrict__ outidx,
    float* __restrict__ rloss) {
  const int lane = threadIdx.x & 63;
  const int row = blockIdx.x * 4 + (threadIdx.x >> 6);
  // lane p holds split p's sorted top-2 (p < SPLITC); butterfly merge -> global top-2
  float v1 = 3.4e38f, v2 = 3.4e38f;
  int i1 = 0x7fffffff, i2 = 0x7fffffff;
  if (lane < SPLITC) {
    const size_t o = ((size_t)lane * TT + row) * 2;
    v1 = bval[o]; v2 = bval[o + 1];
    i1 = bidx[o]; i2 = bidx[o + 1];
  }
#pragma unroll
  for (int m = 1; m < 64; m <<= 1) {
    const float w1 = __shfl_xor(v1, m), w2 = __shfl_xor(v2, m);
    const int j1 = __shfl_xor(i1, m), j2 = __shfl_xor(i2, m);
    if (w1 < v1 || (w1 == v1 && j1 < i1)) {
      if (v1 < w2 || (v1 == w2 && i1 < j2)) { v2 = v1; i2 = i1; }
      else { v2 = w2; i2 = j2; }
      v1 = w1; i1 = j1;
    } else {
      if (w1 < v2 || (w1 == v2 && j1 < i2)) { v2 = w1; i2 = j1; }
    }
  }
  // exact fp32 rescore of both candidates
  const float* xr = x + (size_t)row * DD + lane * 8;
  float e[8], qa[8], qb[8];
  *(float4*)&e[0] = *(const float4*)xr;
  *(float4*)&e[4] = *(const float4*)(xr + 4);
  const float* q1p = imp + (size_t)i1 * DD + lane * 8;
  const float* q2p = imp + (size_t)i2 * DD + lane * 8;
  *(float4*)&qa[0] = *(const float4*)q1p;
  *(float4*)&qa[4] = *(const float4*)(q1p + 4);
  *(float4*)&qb[0] = *(const float4*)q2p;
  *(float4*)&qb[4] = *(const float4*)(q2p + 4);
  float d1 = 0.f, d2 = 0.f;
#pragma unroll
  for (int k = 0; k < 8; ++k) {
    d1 = fmaf(e[k], qa[k], d1);
    d2 = fmaf(e[k], qb[k], d2);
  }
#pragma unroll
  for (int m = 1; m < 64; m <<= 1) {
    d1 += __shfl_xor(d1, m);
    d2 += __shfl_xor(d2, m);
  }
  const float s1 = fmaf(-2.0f, d1, cnorm[i1]);
  const float s2 = fmaf(-2.0f, d2, cnorm[i2]);
  const bool use2 = (s2 < s1) || (s2 == s1 && i2 < i1);
  const int idx = use2 ? i2 : i1;
  float q[8];
#pragma unroll
  for (int k = 0; k < 8; ++k) q[k] = use2 ? qb[k] : qa[k];

  float xx = 0.f, qq = 0.f, xq = 0.f, cl = 0.f;
#pragma unroll
  for (int k = 0; k < 8; ++k) {
    xx = fmaf(e[k], e[k], xx);
    qq = fmaf(q[k], q[k], qq);
    xq = fmaf(e[k], q[k], xq);
    float d = e[k] - q[k] + EPS_PD;
    cl = fmaf(d, d, cl);
  }
#pragma unroll
  for (int m = 1; m < 64; m <<= 1) {
    xx += __shfl_xor(xx, m);
    qq += __shfl_xor(qq, m);
    xq += __shfl_xor(xq, m);
    cl += __shfl_xor(cl, m);
  }
  const float nx = sqrtf(xx), nq = sqrtf(qq);
  const float dx = fmaxf(nx, EPS_DIV), dq = fmaxf(nq, EPS_DIV);
  const float uu = xx / (dx * dx);
  const float qq2 = qq / (dq * dq);
  const float uq = xq / (dx * dq);
  const float ss = uu + qq2 + 2.0f * uq;
  const float dn = fmaxf(sqrtf(ss), EPS_NORM);
  const float es = xx / dx + xq / dq;
  const float a = 2.0f * es / (dn * dn);
  const float b = 2.0f * (xx / dx);
  const float scale = nq / dx;

  float ov[8];
#pragma unroll
  for (int k = 0; k < 8; ++k) {
    const float qp = q[k] / dq;
    const float sk = e[k] / dx + qp;
    ov[k] = (e[k] - a * sk + b * qp) * scale;
  }
  float* op = outq + (size_t)row * DD + lane * 8;
  *(float4*)op = *(const float4*)&ov[0];
  *(float4*)(op + 4) = *(const float4*)&ov[4];
  if (lane == 0) {
    outidx[row] = (float)idx;
    rloss[row] = cl;
  }
}

// ---------------- final loss reduction (deterministic) ----------------
__global__ __launch_bounds__(256) void k_loss_final(
    const float* __restrict__ rloss, float* __restrict__ out) {
  __shared__ double red[256];
  const int tid = threadIdx.x;
  double s = 0.0;
  for (int i = tid; i < TT; i += 256) s += (double)rloss[i];
  red[tid] = s;
  __syncthreads();
  for (int st = 128; st > 0; st >>= 1) {
    if (tid < st) red[tid] += red[tid + st];
    __syncthreads();
  }
  if (tid == 0) out[0] = (float)(red[0] / (double)TT);
}

extern "C" void kernel_launch(void* const* d_in, const int* in_sizes, int n_in,
                              void* d_out, int out_size, void* d_ws, size_t ws_size,
                              hipStream_t stream) {
  const float* x  = (const float*)d_in[0];   // [TT, DD]
  const float* W  = (const float*)d_in[1];   // [DD, DD]
  const float* cb = (const float*)d_in[2];   // [CC, DD]
  float* out = (float*)d_out;

  // workspace layout; xh aliases cbs (cbs dead after k_gemm_mfma)
  float* imp = (float*)d_ws;                             // CC*DD fp32 (16 MiB)
  _Float16* ih = (_Float16*)(imp + (size_t)CC * DD);     // CC*DD f16 (8 MiB)
  _Float16* cbs = ih + (size_t)CC * DD;                  // CC*1024 f16 (16 MiB)
  _Float16* xh = cbs;                                    // TT*DD f16 (16 MiB, alias)
  _Float16* Ws = cbs + (size_t)CC * 1024;                // DD*1024 f16 (1 MiB)
  float* cnorm = (float*)(Ws + (size_t)DD * 1024);       // CC
  float* bval  = cnorm + CC;                             // SPLITC*TT*2 (4 MiB)
  int*   bidx  = (int*)(bval + (size_t)SPLITC * TT * 2); // 4 MiB
  float* rloss = (float*)(bidx + (size_t)SPLITC * TT * 2);

  float* out_q    = out;
  float* out_idx  = out + (size_t)TT * DD;
  float* out_loss = out_idx + TT;

  k_split<<<CC, 128, 0, stream>>>(cb, cbs);
  k_split<<<DD, 128, 0, stream>>>(W, Ws);
  k_gemm_mfma<<<dim3(CC / 128, DD / 128), 256, 0, stream>>>(cbs, Ws, imp, ih);
  k_row_norm2<<<CC / 4, 256, 0, stream>>>(imp, cnorm);
  k_cast16<<<TT, 128, 0, stream>>>(x, xh);
  k_dist_top2<<<dim3(TT / 256, CC / 256), 512, 0, stream>>>(xh, ih, cnorm, bval, bidx);
  k_epilogue<<<TT / 4, 256, 0, stream>>>(x, imp, cnorm, bval, bidx, out_q, out_idx, rloss);
  k_loss_final<<<1, 256, 0, stream>>>(rloss, out_loss);
}

// Round 3
// 338.480 us; speedup vs baseline: 1.0161x; 1.0161x over previous
//
#include <hip/hip_runtime.h>
#include <cstdint>
#include <cstddef>

#define DD 512
#define TT 16384
#define CC 8192
#define SPLITC 32
#define EPS_DIV 1e-6f
#define EPS_NORM 1e-12f
#define EPS_PD 1e-6f

typedef _Float16 half8 __attribute__((ext_vector_type(8)));
typedef _Float16 half4 __attribute__((ext_vector_type(4)));
typedef float floatx4 __attribute__((ext_vector_type(4)));

// async global->LDS, 16B per lane; lds base must be wave-uniform
#define GLDS16(g, l) __builtin_amdgcn_global_load_lds( \
    (const __attribute__((address_space(1))) void*)(g), \
    (__attribute__((address_space(3))) void*)(l), 16, 0, 0)

// ---------------- split fp32 -> (hi, lo) fp16, [row][0:512]=hi [512:1024]=lo ----------------
__global__ __launch_bounds__(128) void k_split(const float* __restrict__ src,
                                               _Float16* __restrict__ dst) {
  const int row = blockIdx.x;
  const int col = threadIdx.x * 4;
  float4 v = *(const float4*)(src + (size_t)row * DD + col);
  half4 h, l;
  h.x = (_Float16)v.x; l.x = (_Float16)(v.x - (float)h.x);
  h.y = (_Float16)v.y; l.y = (_Float16)(v.y - (float)h.y);
  h.z = (_Float16)v.z; l.z = (_Float16)(v.z - (float)h.z);
  h.w = (_Float16)v.w; l.w = (_Float16)(v.w - (float)h.w);
  *(half4*)(dst + (size_t)row * 1024 + col) = h;
  *(half4*)(dst + (size_t)row * 1024 + 512 + col) = l;
}

// ---------------- cast fp32 -> fp16 (hi only), [row][512] ----------------
__global__ __launch_bounds__(128) void k_cast16(const float* __restrict__ src,
                                                _Float16* __restrict__ dst) {
  const int row = blockIdx.x;
  const int col = threadIdx.x * 4;
  float4 v = *(const float4*)(src + (size_t)row * DD + col);
  half4 h;
  h.x = (_Float16)v.x; h.y = (_Float16)v.y;
  h.z = (_Float16)v.z; h.w = (_Float16)v.w;
  *(half4*)(dst + (size_t)row * DD + col) = h;
}

// ---------------- imp = cb @ W^T via split-fp16 3-pass MFMA ----------------
__global__ __launch_bounds__(256) void k_gemm_mfma(
    const _Float16* __restrict__ cbs, const _Float16* __restrict__ Ws,
    float* __restrict__ imp, _Float16* __restrict__ ih) {
  __shared__ __align__(16) char smem[65536];  // A0,B0,A1,B1 @ 16KB each
  const int tid = threadIdx.x;
  const int w = tid >> 6, lane = tid & 63;
  const int quad = lane >> 4, l15 = lane & 15;
  const int wm = (w & 1) * 64, wn = (w >> 1) * 64;
  const int c0 = blockIdx.x * 128;
  const int n0 = blockIdx.y * 128;

  const int srow8 = lane >> 3;
  const int scol = ((lane & 7) ^ srow8) << 3;  // halfs, XOR-swizzled col block
  size_t arow[4], brow[4];
#pragma unroll
  for (int j = 0; j < 4; ++j) {
    arow[j] = (size_t)(c0 + j * 32 + w * 8 + srow8) * 1024 + scol;
    brow[j] = (size_t)(n0 + j * 32 + w * 8 + srow8) * 1024 + scol;
  }
  int aoff[4], boff[4];
#pragma unroll
  for (int i = 0; i < 4; ++i) {
    aoff[i] = ((wm + i * 16 + l15) * 64 + ((quad ^ (l15 & 7)) << 3)) * 2;
    boff[i] = ((wn + i * 16 + l15) * 64 + ((quad ^ (l15 & 7)) << 3)) * 2;
  }

  auto stage = [&](int buf, int ak, int bk) {
    char* ab = smem + buf * 32768;
    char* bb = ab + 16384;
#pragma unroll
    for (int j = 0; j < 4; ++j) {
      GLDS16(cbs + arow[j] + ak, (_Float16*)ab + (j * 32 + w * 8) * 64);
      GLDS16(Ws  + brow[j] + bk, (_Float16*)bb + (j * 32 + w * 8) * 64);
    }
  };

  floatx4 acc[4][4] = {};
  stage(0, 0, 0);
#pragma unroll 2
  for (int it = 0; it < 24; ++it) {   // 3 passes x 8 k-steps
    __syncthreads();
    if (it < 23) {
      const int n = it + 1;
      const int p = n >> 3, kk = n & 7;
      const int ak = ((p == 2) ? 512 : 0) + kk * 64;
      const int bk = ((p == 1) ? 512 : 0) + kk * 64;
      stage(n & 1, ak, bk);
    }
    const char* ab = smem + (it & 1) * 32768;
    const char* bb = ab + 16384;
#pragma unroll
    for (int ks = 0; ks < 2; ++ks) {
      const int kx = ks * 64;  // byte XOR for col-block +4 (rows are 128B here)
      half8 a[4], b[4];
#pragma unroll
      for (int mi = 0; mi < 4; ++mi)
        a[mi] = *(const half8*)(ab + (aoff[mi] ^ kx));
#pragma unroll
      for (int ni = 0; ni < 4; ++ni)
        b[ni] = *(const half8*)(bb + (boff[ni] ^ kx));
#pragma unroll
      for (int mi = 0; mi < 4; ++mi)
#pragma unroll
        for (int ni = 0; ni < 4; ++ni)
          acc[mi][ni] = __builtin_amdgcn_mfma_f32_16x16x32_f16(
              a[mi], b[ni], acc[mi][ni], 0, 0, 0);
    }
  }
  // C/D layout: col=lane&15, row=quad*4+reg
#pragma unroll
  for (int mi = 0; mi < 4; ++mi)
#pragma unroll
    for (int r = 0; r < 4; ++r) {
      const int c = c0 + wm + mi * 16 + quad * 4 + r;
#pragma unroll
      for (int ni = 0; ni < 4; ++ni) {
        const int d = n0 + wn + ni * 16 + l15;
        const float v = acc[mi][ni][r];
        imp[(size_t)c * DD + d] = v;
        ih[(size_t)c * DD + d] = (_Float16)v;
      }
    }
}

// ---------------- per-code squared norms (fp32) ----------------
__global__ __launch_bounds__(256) void k_row_norm2(
    const float* __restrict__ imp, float* __restrict__ cnorm) {
  const int lane = threadIdx.x & 63;
  const int row = blockIdx.x * 4 + (threadIdx.x >> 6);
  const float* p = imp + (size_t)row * DD + lane * 8;
  float4 a = *(const float4*)p;
  float4 b = *(const float4*)(p + 4);
  float s = a.x * a.x + a.y * a.y + a.z * a.z + a.w * a.w +
            b.x * b.x + b.y * b.y + b.z * b.z + b.w * b.w;
#pragma unroll
  for (int m = 1; m < 64; m <<= 1) s += __shfl_xor(s, m);
  if (lane == 0) cnorm[row] = s;
}

// ---------------- phase 1: fp16 hi.hi MFMA scores + per-row TOP-2 ----------------
// 256x256 tile, 8 waves (2Mx4N), chunk=K32, ring-4 x 32KB LDS, m201-style fine
// phases: per chunk 2 phases of {<=8 ds_reads, 2 G-loads, barrier, lgkm, 16 MFMA}.
// Counted vmcnt(8) once per chunk (never 0 until tail). Row-pair XOR swizzle
// (8-slot) on both staging source and ds_read addresses -> conflict-free.
__global__ __launch_bounds__(512, 2) void k_dist_top2(
    const _Float16* __restrict__ xh, const _Float16* __restrict__ ih,
    const float* __restrict__ cnorm,
    float* __restrict__ bval, int* __restrict__ bidx) {
  __shared__ __align__(16) char smem[131072];  // ring: 4 x (A 16KB | B 16KB)
  const int tid = threadIdx.x;
  const int w = tid >> 6, lane = tid & 63;
  const int quad = lane >> 4, l15 = lane & 15;
  const int wr = w >> 2, wc = w & 3;  // 2 (M) x 4 (N) waves, 128x64 per wave
  const int r0 = blockIdx.x * 256;
  const int c0 = blockIdx.y * 256;

  // ---- staging lane mapping (store side of the row-pair XOR swizzle) ----
  // LDS linear: lane l -> unit u=l>>3 (2 rows), slot s=l&7. Content must be
  // global (row = 2u + ((s^u)>>2&1), chunk = (s^u)&3).
  const int se = (lane & 7) ^ ((lane >> 3) & 7);
  const int rl = 2 * (lane >> 3) + ((se >> 2) & 1);    // local row 0..15
  const int chh = (se & 3) * 8;                        // k-chunk offset in halfs
  const _Float16* gA = xh + (size_t)(r0 + w * 32 + rl) * DD + chh;
  const _Float16* gB = ih + (size_t)(c0 + w * 32 + rl) * DD + chh;
  const int ldsW = w * 2048;  // wave's 32-row slice = 16 units * 128B

  // ---- read-side fragment offsets (inverse swizzle) ----
  // row = (wr*128|wc*64) + i*16 + l15, chunk = quad:
  // u = row>>1, slot = (((row&1)<<2)|quad) ^ (u&7); u&7 == (l15>>1)&7 here.
  const int s8 = (((((l15 & 1) << 2) | quad) ^ ((l15 >> 1) & 7))) << 4;  // bytes
  int aoff[8], boff[4];
#pragma unroll
  for (int mi = 0; mi < 8; ++mi)
    aoff[mi] = (wr * 64 + mi * 8 + (l15 >> 1)) * 128 + s8;
#pragma unroll
  for (int ni = 0; ni < 4; ++ni)
    boff[ni] = 16384 + (wc * 32 + ni * 8 + (l15 >> 1)) * 128 + s8;

  float cn[4];
#pragma unroll
  for (int ni = 0; ni < 4; ++ni)
    cn[ni] = cnorm[c0 + wc * 64 + ni * 16 + l15];

  floatx4 acc[8][4] = {};
  half8 aA[4], aB[4], bf[4];

  auto STAGE_A = [&](int t) {
    char* d = smem + (t & 3) * 32768 + ldsW;
    const _Float16* g = gA + (size_t)t * 32;
    GLDS16(g, d);
    GLDS16(g + (size_t)16 * DD, d + 1024);
  };
  auto STAGE_B = [&](int t) {
    char* d = smem + (t & 3) * 32768 + 16384 + ldsW;
    const _Float16* g = gB + (size_t)t * 32;
    GLDS16(g, d);
    GLDS16(g + (size_t)16 * DD, d + 1024);
  };

  // prologue: stage chunks 0..2 (12 loads), retire chunk 0 (vmcnt 8), barrier
  STAGE_A(0); STAGE_B(0);
  STAGE_A(1); STAGE_B(1);
  STAGE_A(2); STAGE_B(2);
  asm volatile("s_waitcnt vmcnt(8)" ::: "memory");
  __builtin_amdgcn_s_barrier();
  __builtin_amdgcn_sched_barrier(0);

// PH0: read aA+bf of chunk T, stage A(T+3), barrier, wait reads, 16 MFMA.
#define PH0(T, DS) {                                                           \
    const char* bb = smem + ((T) & 3) * 32768;                                 \
    _Pragma("unroll")                                                          \
    for (int i = 0; i < 4; ++i) aA[i] = *(const half8*)(bb + aoff[i]);         \
    _Pragma("unroll")                                                          \
    for (int i = 0; i < 4; ++i) bf[i] = *(const half8*)(bb + boff[i]);         \
    if (DS) STAGE_A((T) + 3);                                                  \
    __builtin_amdgcn_s_barrier();                                              \
    asm volatile("s_waitcnt lgkmcnt(0)" ::: "memory");                         \
    __builtin_amdgcn_sched_barrier(0);                                         \
    __builtin_amdgcn_s_setprio(1);                                             \
    _Pragma("unroll")                                                          \
    for (int mi = 0; mi < 4; ++mi)                                             \
      _Pragma("unroll")                                                        \
      for (int ni = 0; ni < 4; ++ni)                                           \
        acc[mi][ni] = __builtin_amdgcn_mfma_f32_16x16x32_f16(                  \
            aA[mi], bf[ni], acc[mi][ni], 0, 0, 0);                             \
    __builtin_amdgcn_s_setprio(0);                                             \
    __builtin_amdgcn_sched_barrier(0);                                         \
  }

// PH1: read aB of chunk T (complete BEFORE barrier -> closes overwrite race),
// stage B(T+3), counted vmcnt (chunk T+1 resident), barrier, 16 MFMA.
#define PH1(T, DS, VMC) {                                                      \
    const char* bb = smem + ((T) & 3) * 32768;                                 \
    _Pragma("unroll")                                                          \
    for (int i = 0; i < 4; ++i) aB[i] = *(const half8*)(bb + aoff[4 + i]);     \
    asm volatile("s_waitcnt lgkmcnt(0)" ::: "memory");                         \
    __builtin_amdgcn_sched_barrier(0);                                         \
    if (DS) STAGE_B((T) + 3);                                                  \
    asm volatile("s_waitcnt vmcnt(" #VMC ")" ::: "memory");                    \
    __builtin_amdgcn_s_barrier();                                              \
    __builtin_amdgcn_sched_barrier(0);                                         \
    __builtin_amdgcn_s_setprio(1);                                             \
    _Pragma("unroll")                                                          \
    for (int mi = 0; mi < 4; ++mi)                                             \
      _Pragma("unroll")                                                        \
      for (int ni = 0; ni < 4; ++ni)                                           \
        acc[4 + mi][ni] = __builtin_amdgcn_mfma_f32_16x16x32_f16(              \
            aB[mi], bf[ni], acc[4 + mi][ni], 0, 0, 0);                         \
    __builtin_amdgcn_s_setprio(0);                                             \
    __builtin_amdgcn_sched_barrier(0);                                         \
  }

  PH0(0, 1)  PH1(0, 1, 8)
  PH0(1, 1)  PH1(1, 1, 8)
  PH0(2, 1)  PH1(2, 1, 8)
  PH0(3, 1)  PH1(3, 1, 8)
  PH0(4, 1)  PH1(4, 1, 8)
  PH0(5, 1)  PH1(5, 1, 8)
  PH0(6, 1)  PH1(6, 1, 8)
  PH0(7, 1)  PH1(7, 1, 8)
  PH0(8, 1)  PH1(8, 1, 8)
  PH0(9, 1)  PH1(9, 1, 8)
  PH0(10, 1) PH1(10, 1, 8)
  PH0(11, 1) PH1(11, 1, 8)
  PH0(12, 1) PH1(12, 1, 8)
  PH0(13, 0) PH1(13, 0, 4)
  PH0(14, 0) PH1(14, 0, 0)
  PH0(15, 0) PH1(15, 0, 0)
#undef PH0
#undef PH1

  // ---- per-row top-2 over the block's 256 codes ----
  __syncthreads();
  float* rv = (float*)smem;            // [256][64] values (64KB), bank-swizzled
  int* ri = (int*)(smem + 65536);      // [256][64] indices (64KB)
#pragma unroll
  for (int mi = 0; mi < 8; ++mi)
#pragma unroll
    for (int r = 0; r < 4; ++r) {
      const int row = wr * 128 + mi * 16 + quad * 4 + r;
      float bv = 3.4e38f; int bi = 0x7fffffff;
#pragma unroll
      for (int ni = 0; ni < 4; ++ni) {
        const float v = fmaf(-2.0f, acc[mi][ni][r], cn[ni]);
        const int c = c0 + wc * 64 + ni * 16 + l15;  // ascends with ni
        if (v < bv) { bv = v; bi = c; }
      }
      const int e = wc * 16 + l15;                   // 0..63
      const int g = (row & 31) ^ ((row & 4) << 2);   // mixes quad bit into bank bit4
      const int col = e ^ g;
      rv[row * 64 + col] = bv;
      ri[row * 64 + col] = bi;
    }
  __syncthreads();
  {
    const int row = tid >> 1, h = tid & 1;           // 2 threads per row
    const int g = (row & 31) ^ ((row & 4) << 2);
    float v1 = 3.4e38f, v2 = 3.4e38f;
    int i1 = 0x7fffffff, i2 = 0x7fffffff;
#pragma unroll
    for (int j = 0; j < 32; ++j) {
      const int e = h * 32 + j;
      const int col = e ^ g;
      const float v = rv[row * 64 + col];
      const int i = ri[row * 64 + col];
      if (v < v1 || (v == v1 && i < i1)) { v2 = v1; i2 = i1; v1 = v; i1 = i; }
      else if (v < v2 || (v == v2 && i < i2)) { v2 = v; i2 = i; }
    }
    const float w1 = __shfl_xor(v1, 1), w2 = __shfl_xor(v2, 1);
    const int j1 = __shfl_xor(i1, 1), j2 = __shfl_xor(i2, 1);
    if (w1 < v1 || (w1 == v1 && j1 < i1)) {
      if (v1 < w2 || (v1 == w2 && i1 < j2)) { v2 = v1; i2 = i1; }
      else { v2 = w2; i2 = j2; }
      v1 = w1; i1 = j1;
    } else if (w1 < v2 || (w1 == v2 && j1 < i2)) { v2 = w1; i2 = j1; }
    if (h == 0) {
      const size_t o = ((size_t)blockIdx.y * TT + r0 + row) * 2;
      bval[o] = v1; bval[o + 1] = v2;
      bidx[o] = i1; bidx[o + 1] = i2;
    }
  }
}

// ---------------- epilogue: butterfly top-2 merge, exact rescore, rotation ----------------
__global__ __launch_bounds__(256) void k_epilogue(
    const float* __restrict__ x, const float* __restrict__ imp,
    const float* __restrict__ cnorm,
    const float* __restrict__ bval, const int* __restrict__ bidx,
    float* __restrict__ outq, float* __restrict__ outidx,
    float* __restrict__ rloss) {
  const int lane = threadIdx.x & 63;
  const int row = blockIdx.x * 4 + (threadIdx.x >> 6);
  // lane p holds split p's sorted top-2 (p < SPLITC); butterfly merge -> global top-2
  float v1 = 3.4e38f, v2 = 3.4e38f;
  int i1 = 0x7fffffff, i2 = 0x7fffffff;
  if (lane < SPLITC) {
    const size_t o = ((size_t)lane * TT + row) * 2;
    v1 = bval[o]; v2 = bval[o + 1];
    i1 = bidx[o]; i2 = bidx[o + 1];
  }
#pragma unroll
  for (int m = 1; m < 64; m <<= 1) {
    const float w1 = __shfl_xor(v1, m), w2 = __shfl_xor(v2, m);
    const int j1 = __shfl_xor(i1, m), j2 = __shfl_xor(i2, m);
    if (w1 < v1 || (w1 == v1 && j1 < i1)) {
      if (v1 < w2 || (v1 == w2 && i1 < j2)) { v2 = v1; i2 = i1; }
      else { v2 = w2; i2 = j2; }
      v1 = w1; i1 = j1;
    } else {
      if (w1 < v2 || (w1 == v2 && j1 < i2)) { v2 = w1; i2 = j1; }
    }
  }
  // exact fp32 rescore of both candidates
  const float* xr = x + (size_t)row * DD + lane * 8;
  float e[8], qa[8], qb[8];
  *(float4*)&e[0] = *(const float4*)xr;
  *(float4*)&e[4] = *(const float4*)(xr + 4);
  const float* q1p = imp + (size_t)i1 * DD + lane * 8;
  const float* q2p = imp + (size_t)i2 * DD + lane * 8;
  *(float4*)&qa[0] = *(const float4*)q1p;
  *(float4*)&qa[4] = *(const float4*)(q1p + 4);
  *(float4*)&qb[0] = *(const float4*)q2p;
  *(float4*)&qb[4] = *(const float4*)(q2p + 4);
  float d1 = 0.f, d2 = 0.f;
#pragma unroll
  for (int k = 0; k < 8; ++k) {
    d1 = fmaf(e[k], qa[k], d1);
    d2 = fmaf(e[k], qb[k], d2);
  }
#pragma unroll
  for (int m = 1; m < 64; m <<= 1) {
    d1 += __shfl_xor(d1, m);
    d2 += __shfl_xor(d2, m);
  }
  const float s1 = fmaf(-2.0f, d1, cnorm[i1]);
  const float s2 = fmaf(-2.0f, d2, cnorm[i2]);
  const bool use2 = (s2 < s1) || (s2 == s1 && i2 < i1);
  const int idx = use2 ? i2 : i1;
  float q[8];
#pragma unroll
  for (int k = 0; k < 8; ++k) q[k] = use2 ? qb[k] : qa[k];

  float xx = 0.f, qq = 0.f, xq = 0.f, cl = 0.f;
#pragma unroll
  for (int k = 0; k < 8; ++k) {
    xx = fmaf(e[k], e[k], xx);
    qq = fmaf(q[k], q[k], qq);
    xq = fmaf(e[k], q[k], xq);
    float d = e[k] - q[k] + EPS_PD;
    cl = fmaf(d, d, cl);
  }
#pragma unroll
  for (int m = 1; m < 64; m <<= 1) {
    xx += __shfl_xor(xx, m);
    qq += __shfl_xor(qq, m);
    xq += __shfl_xor(xq, m);
    cl += __shfl_xor(cl, m);
  }
  const float nx = sqrtf(xx), nq = sqrtf(qq);
  const float dx = fmaxf(nx, EPS_DIV), dq = fmaxf(nq, EPS_DIV);
  const float uu = xx / (dx * dx);
  const float qq2 = qq / (dq * dq);
  const float uq = xq / (dx * dq);
  const float ss = uu + qq2 + 2.0f * uq;
  const float dn = fmaxf(sqrtf(ss), EPS_NORM);
  const float es = xx / dx + xq / dq;
  const float a = 2.0f * es / (dn * dn);
  const float b = 2.0f * (xx / dx);
  const float scale = nq / dx;

  float ov[8];
#pragma unroll
  for (int k = 0; k < 8; ++k) {
    const float qp = q[k] / dq;
    const float sk = e[k] / dx + qp;
    ov[k] = (e[k] - a * sk + b * qp) * scale;
  }
  float* op = outq + (size_t)row * DD + lane * 8;
  *(float4*)op = *(const float4*)&ov[0];
  *(float4*)(op + 4) = *(const float4*)&ov[4];
  if (lane == 0) {
    outidx[row] = (float)idx;
    rloss[row] = cl;
  }
}

// ---------------- final loss reduction (deterministic) ----------------
__global__ __launch_bounds__(256) void k_loss_final(
    const float* __restrict__ rloss, float* __restrict__ out) {
  __shared__ double red[256];
  const int tid = threadIdx.x;
  double s = 0.0;
  for (int i = tid; i < TT; i += 256) s += (double)rloss[i];
  red[tid] = s;
  __syncthreads();
  for (int st = 128; st > 0; st >>= 1) {
    if (tid < st) red[tid] += red[tid + st];
    __syncthreads();
  }
  if (tid == 0) out[0] = (float)(red[0] / (double)TT);
}

extern "C" void kernel_launch(void* const* d_in, const int* in_sizes, int n_in,
                              void* d_out, int out_size, void* d_ws, size_t ws_size,
                              hipStream_t stream) {
  const float* x  = (const float*)d_in[0];   // [TT, DD]
  const float* W  = (const float*)d_in[1];   // [DD, DD]
  const float* cb = (const float*)d_in[2];   // [CC, DD]
  float* out = (float*)d_out;

  // workspace layout; xh aliases cbs (cbs dead after k_gemm_mfma)
  float* imp = (float*)d_ws;                             // CC*DD fp32 (16 MiB)
  _Float16* ih = (_Float16*)(imp + (size_t)CC * DD);     // CC*DD f16 (8 MiB)
  _Float16* cbs = ih + (size_t)CC * DD;                  // CC*1024 f16 (16 MiB)
  _Float16* xh = cbs;                                    // TT*DD f16 (16 MiB, alias)
  _Float16* Ws = cbs + (size_t)CC * 1024;                // DD*1024 f16 (1 MiB)
  float* cnorm = (float*)(Ws + (size_t)DD * 1024);       // CC
  float* bval  = cnorm + CC;                             // SPLITC*TT*2 (4 MiB)
  int*   bidx  = (int*)(bval + (size_t)SPLITC * TT * 2); // 4 MiB
  float* rloss = (float*)(bidx + (size_t)SPLITC * TT * 2);

  float* out_q    = out;
  float* out_idx  = out + (size_t)TT * DD;
  float* out_loss = out_idx + TT;

  k_split<<<CC, 128, 0, stream>>>(cb, cbs);
  k_split<<<DD, 128, 0, stream>>>(W, Ws);
  k_gemm_mfma<<<dim3(CC / 128, DD / 128), 256, 0, stream>>>(cbs, Ws, imp, ih);
  k_row_norm2<<<CC / 4, 256, 0, stream>>>(imp, cnorm);
  k_cast16<<<TT, 128, 0, stream>>>(x, xh);
  k_dist_top2<<<dim3(TT / 256, CC / 256), 512, 0, stream>>>(xh, ih, cnorm, bval, bidx);
  k_epilogue<<<TT / 4, 256, 0, stream>>>(x, imp, cnorm, bval, bidx, out_q, out_idx, rloss);
  k_loss_final<<<1, 256, 0, stream>>>(rloss, out_loss);
}

// Round 4
// 326.905 us; speedup vs baseline: 1.0521x; 1.0354x over previous
//
#include <hip/hip_runtime.h>
#include <cstdint>
#include <cstddef>

#define DD 512
#define TT 16384
#define CC 8192
#define SPLITC 32
#define EPS_DIV 1e-6f
#define EPS_NORM 1e-12f
#define EPS_PD 1e-6f

typedef _Float16 half8 __attribute__((ext_vector_type(8)));
typedef _Float16 half4 __attribute__((ext_vector_type(4)));
typedef float floatx4 __attribute__((ext_vector_type(4)));

// async global->LDS, 16B per lane; lds base must be wave-uniform
#define GLDS16(g, l) __builtin_amdgcn_global_load_lds( \
    (const __attribute__((address_space(1))) void*)(g), \
    (__attribute__((address_space(3))) void*)(l), 16, 0, 0)

// ---------------- split fp32 -> (hi, lo) fp16, [row][0:512]=hi [512:1024]=lo ----------------
__global__ __launch_bounds__(128) void k_split(const float* __restrict__ src,
                                               _Float16* __restrict__ dst) {
  const int row = blockIdx.x;
  const int col = threadIdx.x * 4;
  float4 v = *(const float4*)(src + (size_t)row * DD + col);
  half4 h, l;
  h.x = (_Float16)v.x; l.x = (_Float16)(v.x - (float)h.x);
  h.y = (_Float16)v.y; l.y = (_Float16)(v.y - (float)h.y);
  h.z = (_Float16)v.z; l.z = (_Float16)(v.z - (float)h.z);
  h.w = (_Float16)v.w; l.w = (_Float16)(v.w - (float)h.w);
  *(half4*)(dst + (size_t)row * 1024 + col) = h;
  *(half4*)(dst + (size_t)row * 1024 + 512 + col) = l;
}

// ---------------- cast fp32 -> fp16 (hi only), [row][512] ----------------
__global__ __launch_bounds__(128) void k_cast16(const float* __restrict__ src,
                                                _Float16* __restrict__ dst) {
  const int row = blockIdx.x;
  const int col = threadIdx.x * 4;
  float4 v = *(const float4*)(src + (size_t)row * DD + col);
  half4 h;
  h.x = (_Float16)v.x; h.y = (_Float16)v.y;
  h.z = (_Float16)v.z; h.w = (_Float16)v.w;
  *(half4*)(dst + (size_t)row * DD + col) = h;
}

// ---------------- imp = cb @ W^T via split-fp16 3-pass MFMA ----------------
__global__ __launch_bounds__(256) void k_gemm_mfma(
    const _Float16* __restrict__ cbs, const _Float16* __restrict__ Ws,
    float* __restrict__ imp, _Float16* __restrict__ ih) {
  __shared__ __align__(16) char smem[65536];  // A0,B0,A1,B1 @ 16KB each
  const int tid = threadIdx.x;
  const int w = tid >> 6, lane = tid & 63;
  const int quad = lane >> 4, l15 = lane & 15;
  const int wm = (w & 1) * 64, wn = (w >> 1) * 64;
  const int c0 = blockIdx.x * 128;
  const int n0 = blockIdx.y * 128;

  const int srow8 = lane >> 3;
  const int scol = ((lane & 7) ^ srow8) << 3;  // halfs, XOR-swizzled col block
  size_t arow[4], brow[4];
#pragma unroll
  for (int j = 0; j < 4; ++j) {
    arow[j] = (size_t)(c0 + j * 32 + w * 8 + srow8) * 1024 + scol;
    brow[j] = (size_t)(n0 + j * 32 + w * 8 + srow8) * 1024 + scol;
  }
  int aoff[4], boff[4];
#pragma unroll
  for (int i = 0; i < 4; ++i) {
    aoff[i] = ((wm + i * 16 + l15) * 64 + ((quad ^ (l15 & 7)) << 3)) * 2;
    boff[i] = ((wn + i * 16 + l15) * 64 + ((quad ^ (l15 & 7)) << 3)) * 2;
  }

  auto stage = [&](int buf, int ak, int bk) {
    char* ab = smem + buf * 32768;
    char* bb = ab + 16384;
#pragma unroll
    for (int j = 0; j < 4; ++j) {
      GLDS16(cbs + arow[j] + ak, (_Float16*)ab + (j * 32 + w * 8) * 64);
      GLDS16(Ws  + brow[j] + bk, (_Float16*)bb + (j * 32 + w * 8) * 64);
    }
  };

  floatx4 acc[4][4] = {};
  stage(0, 0, 0);
#pragma unroll 2
  for (int it = 0; it < 24; ++it) {   // 3 passes x 8 k-steps
    __syncthreads();
    if (it < 23) {
      const int n = it + 1;
      const int p = n >> 3, kk = n & 7;
      const int ak = ((p == 2) ? 512 : 0) + kk * 64;
      const int bk = ((p == 1) ? 512 : 0) + kk * 64;
      stage(n & 1, ak, bk);
    }
    const char* ab = smem + (it & 1) * 32768;
    const char* bb = ab + 16384;
#pragma unroll
    for (int ks = 0; ks < 2; ++ks) {
      const int kx = ks * 64;  // byte XOR for col-block +4 (rows are 128B here)
      half8 a[4], b[4];
#pragma unroll
      for (int mi = 0; mi < 4; ++mi)
        a[mi] = *(const half8*)(ab + (aoff[mi] ^ kx));
#pragma unroll
      for (int ni = 0; ni < 4; ++ni)
        b[ni] = *(const half8*)(bb + (boff[ni] ^ kx));
#pragma unroll
      for (int mi = 0; mi < 4; ++mi)
#pragma unroll
        for (int ni = 0; ni < 4; ++ni)
          acc[mi][ni] = __builtin_amdgcn_mfma_f32_16x16x32_f16(
              a[mi], b[ni], acc[mi][ni], 0, 0, 0);
    }
  }
  // C/D layout: col=lane&15, row=quad*4+reg
#pragma unroll
  for (int mi = 0; mi < 4; ++mi)
#pragma unroll
    for (int r = 0; r < 4; ++r) {
      const int c = c0 + wm + mi * 16 + quad * 4 + r;
#pragma unroll
      for (int ni = 0; ni < 4; ++ni) {
        const int d = n0 + wn + ni * 16 + l15;
        const float v = acc[mi][ni][r];
        imp[(size_t)c * DD + d] = v;
        ih[(size_t)c * DD + d] = (_Float16)v;
      }
    }
}

// ---------------- per-code squared norms (fp32) ----------------
__global__ __launch_bounds__(256) void k_row_norm2(
    const float* __restrict__ imp, float* __restrict__ cnorm) {
  const int lane = threadIdx.x & 63;
  const int row = blockIdx.x * 4 + (threadIdx.x >> 6);
  const float* p = imp + (size_t)row * DD + lane * 8;
  float4 a = *(const float4*)p;
  float4 b = *(const float4*)(p + 4);
  float s = a.x * a.x + a.y * a.y + a.z * a.z + a.w * a.w +
            b.x * b.x + b.y * b.y + b.z * b.z + b.w * b.w;
#pragma unroll
  for (int m = 1; m < 64; m <<= 1) s += __shfl_xor(s, m);
  if (lane == 0) cnorm[row] = s;
}

// ---------------- phase 1: fp16 hi.hi MFMA scores + per-row TOP-2 ----------------
// 256x256 tile, 8 waves (2Mx4N), chunk=K32, ring-4 x 32KB LDS, m201-faithful
// phases: PH0={8 ds_read, 2 GLDS, bar, lgkm0, 16 MFMA, bar},
//         PH1={4 ds_read, 2 GLDS, vmcnt(8) counted, bar, lgkm0, 16 MFMA, bar}.
// Depth-3 prefetch; residency of chunk t+1 established by PH1(t)'s vmcnt+bar,
// so every phase's ds_reads sit BEFORE the barrier and drain under it.
__global__ __launch_bounds__(512, 2) void k_dist_top2(
    const _Float16* __restrict__ xh, const _Float16* __restrict__ ih,
    const float* __restrict__ cnorm,
    float* __restrict__ bval, int* __restrict__ bidx) {
  __shared__ __align__(16) char smem[131072];  // ring: 4 x (A 16KB | B 16KB)
  const int tid = threadIdx.x;
  const int w = tid >> 6, lane = tid & 63;
  const int quad = lane >> 4, l15 = lane & 15;
  const int wr = w >> 2, wc = w & 3;  // 2 (M) x 4 (N) waves, 128x64 per wave
  const int r0 = blockIdx.x * 256;
  const int c0 = blockIdx.y * 256;

  // ---- staging lane mapping (store side of the row-pair XOR swizzle) ----
  const int se = (lane & 7) ^ ((lane >> 3) & 7);
  const int rl = 2 * (lane >> 3) + ((se >> 2) & 1);    // local row 0..15
  const int chh = (se & 3) * 8;                        // k-chunk offset in halfs
  const _Float16* gA = xh + (size_t)(r0 + w * 32 + rl) * DD + chh;
  const _Float16* gB = ih + (size_t)(c0 + w * 32 + rl) * DD + chh;
  const int ldsW = w * 2048;  // wave's 32-row slice = 16 units * 128B

  // ---- read-side fragment offsets (inverse swizzle) ----
  const int s8 = (((((l15 & 1) << 2) | quad) ^ ((l15 >> 1) & 7))) << 4;  // bytes
  int aoff[8], boff[4];
#pragma unroll
  for (int mi = 0; mi < 8; ++mi)
    aoff[mi] = (wr * 64 + mi * 8 + (l15 >> 1)) * 128 + s8;
#pragma unroll
  for (int ni = 0; ni < 4; ++ni)
    boff[ni] = 16384 + (wc * 32 + ni * 8 + (l15 >> 1)) * 128 + s8;

  float cn[4];
#pragma unroll
  for (int ni = 0; ni < 4; ++ni)
    cn[ni] = cnorm[c0 + wc * 64 + ni * 16 + l15];

  floatx4 acc[8][4] = {};
  half8 aM[4], bN[4];

  auto STAGE_A = [&](int t) {
    char* d = smem + (t & 3) * 32768 + ldsW;
    const _Float16* g = gA + (size_t)t * 32;
    GLDS16(g, d);
    GLDS16(g + (size_t)16 * DD, d + 1024);
  };
  auto STAGE_B = [&](int t) {
    char* d = smem + (t & 3) * 32768 + 16384 + ldsW;
    const _Float16* g = gB + (size_t)t * 32;
    GLDS16(g, d);
    GLDS16(g + (size_t)16 * DD, d + 1024);
  };

  // prologue: stage chunks 0..2 (12 loads), retire chunk 0 (vmcnt 8), barrier
  STAGE_A(0); STAGE_B(0);
  STAGE_A(1); STAGE_B(1);
  STAGE_A(2); STAGE_B(2);
  asm volatile("s_waitcnt vmcnt(8)" ::: "memory");
  __builtin_amdgcn_s_barrier();
  __builtin_amdgcn_sched_barrier(0);

#define VM8 asm volatile("s_waitcnt vmcnt(8)" ::: "memory");
#define VM4 asm volatile("s_waitcnt vmcnt(4)" ::: "memory");
#define VM0 asm volatile("s_waitcnt vmcnt(0)" ::: "memory");
#define VMN

// PH0: 8 ds_reads (aM0-3 + all bN) of chunk T, stage A(T+3), barrier,
// lgkm drain, 16 MFMA (acc rows 0-3), barrier.
#define PH0(T, DS) {                                                           \
    const char* bb = smem + ((T) & 3) * 32768;                                 \
    _Pragma("unroll")                                                          \
    for (int i = 0; i < 4; ++i) aM[i] = *(const half8*)(bb + aoff[i]);         \
    _Pragma("unroll")                                                          \
    for (int i = 0; i < 4; ++i) bN[i] = *(const half8*)(bb + boff[i]);         \
    if (DS) STAGE_A((T) + 3);                                                  \
    __builtin_amdgcn_s_barrier();                                              \
    asm volatile("s_waitcnt lgkmcnt(0)" ::: "memory");                         \
    __builtin_amdgcn_sched_barrier(0);                                         \
    __builtin_amdgcn_s_setprio(1);                                             \
    _Pragma("unroll")                                                          \
    for (int mi = 0; mi < 4; ++mi)                                             \
      _Pragma("unroll")                                                        \
      for (int ni = 0; ni < 4; ++ni)                                           \
        acc[mi][ni] = __builtin_amdgcn_mfma_f32_16x16x32_f16(                  \
            aM[mi], bN[ni], acc[mi][ni], 0, 0, 0);                             \
    __builtin_amdgcn_s_setprio(0);                                             \
    __builtin_amdgcn_sched_barrier(0);                                         \
    __builtin_amdgcn_s_barrier();                                              \
  }

// PH1: 4 ds_reads (aM4-7) of chunk T, stage B(T+3), counted vmcnt (chunk T+1
// resident; in-order retirement), barrier, lgkm drain, 16 MFMA (rows 4-7), barrier.
#define PH1(T, DS, VW) {                                                       \
    const char* bb = smem + ((T) & 3) * 32768;                                 \
    _Pragma("unroll")                                                          \
    for (int i = 0; i < 4; ++i) aM[i] = *(const half8*)(bb + aoff[4 + i]);     \
    if (DS) STAGE_B((T) + 3);                                                  \
    VW                                                                         \
    __builtin_amdgcn_s_barrier();                                              \
    asm volatile("s_waitcnt lgkmcnt(0)" ::: "memory");                         \
    __builtin_amdgcn_sched_barrier(0);                                         \
    __builtin_amdgcn_s_setprio(1);                                             \
    _Pragma("unroll")                                                          \
    for (int mi = 0; mi < 4; ++mi)                                             \
      _Pragma("unroll")                                                        \
      for (int ni = 0; ni < 4; ++ni)                                           \
        acc[4 + mi][ni] = __builtin_amdgcn_mfma_f32_16x16x32_f16(              \
            aM[mi], bN[ni], acc[4 + mi][ni], 0, 0, 0);                         \
    __builtin_amdgcn_s_setprio(0);                                             \
    __builtin_amdgcn_sched_barrier(0);                                         \
    __builtin_amdgcn_s_barrier();                                              \
  }

  PH0(0, 1)  PH1(0, 1, VM8)
  PH0(1, 1)  PH1(1, 1, VM8)
  PH0(2, 1)  PH1(2, 1, VM8)
  PH0(3, 1)  PH1(3, 1, VM8)
  PH0(4, 1)  PH1(4, 1, VM8)
  PH0(5, 1)  PH1(5, 1, VM8)
  PH0(6, 1)  PH1(6, 1, VM8)
  PH0(7, 1)  PH1(7, 1, VM8)
  PH0(8, 1)  PH1(8, 1, VM8)
  PH0(9, 1)  PH1(9, 1, VM8)
  PH0(10, 1) PH1(10, 1, VM8)
  PH0(11, 1) PH1(11, 1, VM8)
  PH0(12, 1) PH1(12, 1, VM8)
  PH0(13, 0) PH1(13, 0, VM4)
  PH0(14, 0) PH1(14, 0, VM0)
  PH0(15, 0) PH1(15, 0, VMN)
#undef PH0
#undef PH1
#undef VM8
#undef VM4
#undef VM0
#undef VMN

  // ---- per-row top-2 over the block's 256 codes ----
  __syncthreads();
  float* rv = (float*)smem;            // [256][64] values (64KB), bank-swizzled
  int* ri = (int*)(smem + 65536);      // [256][64] indices (64KB)
#pragma unroll
  for (int mi = 0; mi < 8; ++mi)
#pragma unroll
    for (int r = 0; r < 4; ++r) {
      const int row = wr * 128 + mi * 16 + quad * 4 + r;
      float bv = 3.4e38f; int bi = 0x7fffffff;
#pragma unroll
      for (int ni = 0; ni < 4; ++ni) {
        const float v = fmaf(-2.0f, acc[mi][ni][r], cn[ni]);
        const int c = c0 + wc * 64 + ni * 16 + l15;  // ascends with ni
        if (v < bv) { bv = v; bi = c; }
      }
      const int e = wc * 16 + l15;                   // 0..63
      const int g = (row & 31) ^ ((row & 4) << 2);   // mixes quad bit into bank bit4
      const int col = e ^ g;
      rv[row * 64 + col] = bv;
      ri[row * 64 + col] = bi;
    }
  __syncthreads();
  {
    const int row = tid >> 1, h = tid & 1;           // 2 threads per row
    const int g = (row & 31) ^ ((row & 4) << 2);
    float v1 = 3.4e38f, v2 = 3.4e38f;
    int i1 = 0x7fffffff, i2 = 0x7fffffff;
#pragma unroll
    for (int j = 0; j < 32; ++j) {
      const int e = h * 32 + j;
      const int col = e ^ g;
      const float v = rv[row * 64 + col];
      const int i = ri[row * 64 + col];
      if (v < v1 || (v == v1 && i < i1)) { v2 = v1; i2 = i1; v1 = v; i1 = i; }
      else if (v < v2 || (v == v2 && i < i2)) { v2 = v; i2 = i; }
    }
    const float w1 = __shfl_xor(v1, 1), w2 = __shfl_xor(v2, 1);
    const int j1 = __shfl_xor(i1, 1), j2 = __shfl_xor(i2, 1);
    if (w1 < v1 || (w1 == v1 && j1 < i1)) {
      if (v1 < w2 || (v1 == w2 && i1 < j2)) { v2 = v1; i2 = i1; }
      else { v2 = w2; i2 = j2; }
      v1 = w1; i1 = j1;
    } else if (w1 < v2 || (w1 == v2 && j1 < i2)) { v2 = w1; i2 = j1; }
    if (h == 0) {
      const size_t o = ((size_t)blockIdx.y * TT + r0 + row) * 2;
      bval[o] = v1; bval[o + 1] = v2;
      bidx[o] = i1; bidx[o + 1] = i2;
    }
  }
}

// ---------------- epilogue: butterfly top-2 merge, exact rescore, rotation ----------------
__global__ __launch_bounds__(256) void k_epilogue(
    const float* __restrict__ x, const float* __restrict__ imp,
    const float* __restrict__ cnorm,
    const float* __restrict__ bval, const int* __restrict__ bidx,
    float* __restrict__ outq, float* __restrict__ outidx,
    float* __restrict__ rloss) {
  const int lane = threadIdx.x & 63;
  const int row = blockIdx.x * 4 + (threadIdx.x >> 6);
  // lane p holds split p's sorted top-2 (p < SPLITC); butterfly merge -> global top-2
  float v1 = 3.4e38f, v2 = 3.4e38f;
  int i1 = 0x7fffffff, i2 = 0x7fffffff;
  if (lane < SPLITC) {
    const size_t o = ((size_t)lane * TT + row) * 2;
    v1 = bval[o]; v2 = bval[o + 1];
    i1 = bidx[o]; i2 = bidx[o + 1];
  }
#pragma unroll
  for (int m = 1; m < 64; m <<= 1) {
    const float w1 = __shfl_xor(v1, m), w2 = __shfl_xor(v2, m);
    const int j1 = __shfl_xor(i1, m), j2 = __shfl_xor(i2, m);
    if (w1 < v1 || (w1 == v1 && j1 < i1)) {
      if (v1 < w2 || (v1 == w2 && i1 < j2)) { v2 = v1; i2 = i1; }
      else { v2 = w2; i2 = j2; }
      v1 = w1; i1 = j1;
    } else {
      if (w1 < v2 || (w1 == v2 && j1 < i2)) { v2 = w1; i2 = j1; }
    }
  }
  // exact fp32 rescore of both candidates
  const float* xr = x + (size_t)row * DD + lane * 8;
  float e[8], qa[8], qb[8];
  *(float4*)&e[0] = *(const float4*)xr;
  *(float4*)&e[4] = *(const float4*)(xr + 4);
  const float* q1p = imp + (size_t)i1 * DD + lane * 8;
  const float* q2p = imp + (size_t)i2 * DD + lane * 8;
  *(float4*)&qa[0] = *(const float4*)q1p;
  *(float4*)&qa[4] = *(const float4*)(q1p + 4);
  *(float4*)&qb[0] = *(const float4*)q2p;
  *(float4*)&qb[4] = *(const float4*)(q2p + 4);
  float d1 = 0.f, d2 = 0.f;
#pragma unroll
  for (int k = 0; k < 8; ++k) {
    d1 = fmaf(e[k], qa[k], d1);
    d2 = fmaf(e[k], qb[k], d2);
  }
#pragma unroll
  for (int m = 1; m < 64; m <<= 1) {
    d1 += __shfl_xor(d1, m);
    d2 += __shfl_xor(d2, m);
  }
  const float s1 = fmaf(-2.0f, d1, cnorm[i1]);
  const float s2 = fmaf(-2.0f, d2, cnorm[i2]);
  const bool use2 = (s2 < s1) || (s2 == s1 && i2 < i1);
  const int idx = use2 ? i2 : i1;
  float q[8];
#pragma unroll
  for (int k = 0; k < 8; ++k) q[k] = use2 ? qb[k] : qa[k];

  float xx = 0.f, qq = 0.f, xq = 0.f, cl = 0.f;
#pragma unroll
  for (int k = 0; k < 8; ++k) {
    xx = fmaf(e[k], e[k], xx);
    qq = fmaf(q[k], q[k], qq);
    xq = fmaf(e[k], q[k], xq);
    float d = e[k] - q[k] + EPS_PD;
    cl = fmaf(d, d, cl);
  }
#pragma unroll
  for (int m = 1; m < 64; m <<= 1) {
    xx += __shfl_xor(xx, m);
    qq += __shfl_xor(qq, m);
    xq += __shfl_xor(xq, m);
    cl += __shfl_xor(cl, m);
  }
  const float nx = sqrtf(xx), nq = sqrtf(qq);
  const float dx = fmaxf(nx, EPS_DIV), dq = fmaxf(nq, EPS_DIV);
  const float uu = xx / (dx * dx);
  const float qq2 = qq / (dq * dq);
  const float uq = xq / (dx * dq);
  const float ss = uu + qq2 + 2.0f * uq;
  const float dn = fmaxf(sqrtf(ss), EPS_NORM);
  const float es = xx / dx + xq / dq;
  const float a = 2.0f * es / (dn * dn);
  const float b = 2.0f * (xx / dx);
  const float scale = nq / dx;

  float ov[8];
#pragma unroll
  for (int k = 0; k < 8; ++k) {
    const float qp = q[k] / dq;
    const float sk = e[k] / dx + qp;
    ov[k] = (e[k] - a * sk + b * qp) * scale;
  }
  float* op = outq + (size_t)row * DD + lane * 8;
  *(float4*)op = *(const float4*)&ov[0];
  *(float4*)(op + 4) = *(const float4*)&ov[4];
  if (lane == 0) {
    outidx[row] = (float)idx;
    rloss[row] = cl;
  }
}

// ---------------- final loss reduction (deterministic) ----------------
__global__ __launch_bounds__(256) void k_loss_final(
    const float* __restrict__ rloss, float* __restrict__ out) {
  __shared__ double red[256];
  const int tid = threadIdx.x;
  double s = 0.0;
  for (int i = tid; i < TT; i += 256) s += (double)rloss[i];
  red[tid] = s;
  __syncthreads();
  for (int st = 128; st > 0; st >>= 1) {
    if (tid < st) red[tid] += red[tid + st];
    __syncthreads();
  }
  if (tid == 0) out[0] = (float)(red[0] / (double)TT);
}

extern "C" void kernel_launch(void* const* d_in, const int* in_sizes, int n_in,
                              void* d_out, int out_size, void* d_ws, size_t ws_size,
                              hipStream_t stream) {
  const float* x  = (const float*)d_in[0];   // [TT, DD]
  const float* W  = (const float*)d_in[1];   // [DD, DD]
  const float* cb = (const float*)d_in[2];   // [CC, DD]
  float* out = (float*)d_out;

  // workspace layout; xh aliases cbs (cbs dead after k_gemm_mfma)
  float* imp = (float*)d_ws;                             // CC*DD fp32 (16 MiB)
  _Float16* ih = (_Float16*)(imp + (size_t)CC * DD);     // CC*DD f16 (8 MiB)
  _Float16* cbs = ih + (size_t)CC * DD;                  // CC*1024 f16 (16 MiB)
  _Float16* xh = cbs;                                    // TT*DD f16 (16 MiB, alias)
  _Float16* Ws = cbs + (size_t)CC * 1024;                // DD*1024 f16 (1 MiB)
  float* cnorm = (float*)(Ws + (size_t)DD * 1024);       // CC
  float* bval  = cnorm + CC;                             // SPLITC*TT*2 (4 MiB)
  int*   bidx  = (int*)(bval + (size_t)SPLITC * TT * 2); // 4 MiB
  float* rloss = (float*)(bidx + (size_t)SPLITC * TT * 2);

  float* out_q    = out;
  float* out_idx  = out + (size_t)TT * DD;
  float* out_loss = out_idx + TT;

  k_split<<<CC, 128, 0, stream>>>(cb, cbs);
  k_split<<<DD, 128, 0, stream>>>(W, Ws);
  k_gemm_mfma<<<dim3(CC / 128, DD / 128), 256, 0, stream>>>(cbs, Ws, imp, ih);
  k_row_norm2<<<CC / 4, 256, 0, stream>>>(imp, cnorm);
  k_cast16<<<TT, 128, 0, stream>>>(x, xh);
  k_dist_top2<<<dim3(TT / 256, CC / 256), 512, 0, stream>>>(xh, ih, cnorm, bval, bidx);
  k_epilogue<<<TT / 4, 256, 0, stream>>>(x, imp, cnorm, bval, bidx, out_q, out_idx, rloss);
  k_loss_final<<<1, 256, 0, stream>>>(rloss, out_loss);
}